// Round 10
// baseline (3716.444 us; speedup 1.0000x reference)
//
#include <hip/hip_runtime.h>

typedef unsigned int uint;
typedef unsigned short ushort;

#define M1 1024
#define MH 512
#define PI_F 3.14159265358979323846f
#define LBOX 10.0f
#define NB 32

__device__ __forceinline__ float bf2f(ushort h){ return __uint_as_float(((uint)h)<<16); }
__device__ __forceinline__ ushort f2bf(float f){ uint u = __float_as_uint(f); uint r = (u + 0x7fffu + ((u>>16)&1u))>>16; return (ushort)r; }
__device__ __forceinline__ float ftanh(float x){ float e = __expf(2.f*x); return 1.f - 2.f/(e+1.f); }
__device__ __forceinline__ float2 cmul(float2 a, float2 b){ return make_float2(a.x*b.x - a.y*b.y, a.x*b.y + a.y*b.x); }
__device__ __forceinline__ void cfma(float2& c, float2 a, float2 b){
  c.x = fmaf(a.x,b.x,fmaf(-a.y,b.y,c.x));
  c.y = fmaf(a.x,b.y,fmaf(a.y,b.x,c.y));
}
__device__ __forceinline__ float2 shfl2(float2 v, int src){
  return make_float2(__shfl(v.x, src), __shfl(v.y, src));
}

// 31 Fourier features: [r, cos(k=1,d0..2), sin(k=1,d0..2), ..., k=5]
__device__ __forceinline__ void fourier31(float d0, float d1, float d2, bool diag, float f[31]){
  const float k1 = PI_F / LBOX;
  float s[3], c[3];
  __sincosf(k1*d0, &s[0], &c[0]);
  __sincosf(k1*d1, &s[1], &c[1]);
  __sincosf(k1*d2, &s[2], &c[2]);
  float r = diag ? 0.f : (LBOX/PI_F)*sqrtf(s[0]*s[0]+s[1]*s[1]+s[2]*s[2]);
  f[0] = r;
  float cb[3], sb[3], cc[3], sc[3];
  #pragma unroll
  for (int d=0; d<3; ++d){ cb[d] = 1.f - 2.f*s[d]*s[d]; sb[d] = 2.f*s[d]*c[d]; cc[d]=cb[d]; sc[d]=sb[d]; }
  #pragma unroll
  for (int k=0;k<5;++k){
    #pragma unroll
    for (int d=0; d<3; ++d){ f[1+6*k+d] = cc[d]; f[4+6*k+d] = sc[d]; }
    if (k<4){
      #pragma unroll
      for (int d=0; d<3; ++d){
        float nc = cc[d]*cb[d]-sc[d]*sb[d];
        float ns = sc[d]*cb[d]+cc[d]*sb[d];
        cc[d]=nc; sc[d]=ns;
      }
    }
  }
}

__global__ void k_zero(float* __restrict__ p, int n){
  int i = blockIdx.x*256 + threadIdx.x;
  int st = gridDim.x*256;
  for (; i<n; i+=st) p[i] = 0.f;
}

__global__ void k_iota(int* __restrict__ rowmap){
  int q = blockIdx.x*256 + threadIdx.x;
  rowmap[q] = q & 511;
}

// layer-0: fourier feats -> tanh(f @ W31x16 + b), store bf16 [i][j][16].
// FUSED: also block-reduces the 31 raw features and atomically accumulates
// row-sums (see k_e0 for the symmetry-based column-sum recovery).
__global__ __launch_bounds__(256) void k_pair0(const float* __restrict__ sx, const float* __restrict__ W,
                                               const float* __restrict__ b, ushort* __restrict__ out, int is_ee,
                                               float* __restrict__ gA, float* __restrict__ gB){
  int bx = blockIdx.x;
  int i = bx >> 2;
  int chunk = bx & 3;
  int j = (chunk << 8) + threadIdx.x;
  const float* xs = sx + 3*M1;
  float xi0 = xs[3*i], xi1 = xs[3*i+1], xi2 = xs[3*i+2];
  const float* oth = is_ee ? xs : sx;
  float y0 = oth[3*j], y1 = oth[3*j+1], y2 = oth[3*j+2];
  float f[31];
  fourier31(xi0-y0, xi1-y1, xi2-y2, is_ee && (i==j), f);
  float acc[16];
  #pragma unroll
  for (int o=0;o<16;++o) acc[o] = b[o];
  #pragma unroll
  for (int c=0;c<31;++c){ float fv = f[c];
    #pragma unroll
    for (int o=0;o<16;++o) acc[o] = fmaf(fv, W[c*16+o], acc[o]);
  }
  uint u[8];
  #pragma unroll
  for (int h=0;h<8;++h){
    ushort lo = f2bf(ftanh(acc[2*h]));
    ushort hi = f2bf(ftanh(acc[2*h+1]));
    u[h] = (uint)lo | ((uint)hi<<16);
  }
  uint4* dst = (uint4*)(out + ((size_t)i*M1 + j)*16);
  dst[0] = make_uint4(u[0],u[1],u[2],u[3]);
  dst[1] = make_uint4(u[4],u[5],u[6],u[7]);
  // block tree-reduction of the 31 raw features over 256 threads
  __shared__ float buf[256*33];
  #pragma unroll
  for (int c=0;c<31;++c) buf[threadIdx.x*33+c] = f[c];
  __syncthreads();
  #pragma unroll
  for (int s=128; s>0; s>>=1){
    if (threadIdx.x < s){
      #pragma unroll
      for (int c=0;c<31;++c) buf[threadIdx.x*33+c] += buf[(threadIdx.x+s)*33+c];
    }
    __syncthreads();
  }
  if (threadIdx.x < 31){
    float* g = (is_ee && chunk >= 2) ? gB : gA;
    atomicAdd(&g[i*31+threadIdx.x], buf[threadIdx.x]);
  }
}

// layers 1..2: in-place ten = tanh(ten @ W16x16 + b) + ten
__global__ __launch_bounds__(256) void k_pairU(ushort* __restrict__ ten, const float* __restrict__ W,
                                               const float* __restrict__ b){
  size_t base = ((size_t)blockIdx.x*256 + threadIdx.x)*16;
  uint4 a0 = ((uint4*)(ten+base))[0];
  uint4 a1 = ((uint4*)(ten+base))[1];
  uint uu[8] = {a0.x,a0.y,a0.z,a0.w,a1.x,a1.y,a1.z,a1.w};
  float v[16];
  #pragma unroll
  for (int h=0;h<8;++h){ v[2*h] = bf2f((ushort)(uu[h]&0xffffu)); v[2*h+1] = bf2f((ushort)(uu[h]>>16)); }
  float acc[16];
  #pragma unroll
  for (int o=0;o<16;++o) acc[o] = b[o];
  #pragma unroll
  for (int c=0;c<16;++c){ float fv = v[c];
    #pragma unroll
    for (int o=0;o<16;++o) acc[o] = fmaf(fv, W[c*16+o], acc[o]);
  }
  uint w[8];
  #pragma unroll
  for (int h=0;h<8;++h){
    float q0 = ftanh(acc[2*h]) + v[2*h];
    float q1 = ftanh(acc[2*h+1]) + v[2*h+1];
    w[h] = (uint)f2bf(q0) | ((uint)f2bf(q1)<<16);
  }
  ((uint4*)(ten+base))[0] = make_uint4(w[0],w[1],w[2],w[3]);
  ((uint4*)(ten+base))[1] = make_uint4(w[4],w[5],w[6],w[7]);
}

// half-column means of a bf16 [1024][1024][16] tensor (sum over i<512 -> gA, i>=512 -> gB), atomic
__global__ __launch_bounds__(256) void k_gee(const ushort* __restrict__ ten, float* __restrict__ gA, float* __restrict__ gB){
  int jb = blockIdx.x >> 3;
  int ic = blockIdx.x & 7;
  int jl = threadIdx.x & 63;
  int iq = threadIdx.x >> 6;
  int j = jb*64 + jl;
  float acc[16];
  #pragma unroll
  for (int c=0;c<16;++c) acc[c]=0.f;
  for (int s=0;s<32;++s){
    int i = ic*128 + iq + 4*s;
    const uint4* src = (const uint4*)(ten + ((size_t)i*M1 + j)*16);
    uint4 a0 = src[0], a1 = src[1];
    uint uu[8]={a0.x,a0.y,a0.z,a0.w,a1.x,a1.y,a1.z,a1.w};
    #pragma unroll
    for (int h=0;h<8;++h){ acc[2*h]+=bf2f((ushort)(uu[h]&0xffffu)); acc[2*h+1]+=bf2f((ushort)(uu[h]>>16)); }
  }
  __shared__ float red[4][64][16];
  #pragma unroll
  for (int c=0;c<16;++c) red[iq][jl][c]=acc[c];
  __syncthreads();
  if (iq==0){
    float* out = (ic<4)? gA : gB;
    #pragma unroll
    for (int c=0;c<16;++c){
      float t = red[0][jl][c]+red[1][jl][c]+red[2][jl][c]+red[3][jl][c];
      atomicAdd(&out[j*16+c], t);
    }
  }
}

// row means of bf16 tensor (sum over j) -> direct write
__global__ __launch_bounds__(256) void k_gep(const ushort* __restrict__ ten, float* __restrict__ g3){
  int ib = blockIdx.x;
  int il = threadIdx.x >> 6;
  int jl = threadIdx.x & 63;
  int i = ib*4 + il;
  float acc[16];
  #pragma unroll
  for (int c=0;c<16;++c) acc[c]=0.f;
  for (int s=0;s<16;++s){
    int j = jl + 64*s;
    const uint4* src = (const uint4*)(ten + ((size_t)i*M1 + j)*16);
    uint4 a0 = src[0], a1 = src[1];
    uint uu[8]={a0.x,a0.y,a0.z,a0.w,a1.x,a1.y,a1.z,a1.w};
    #pragma unroll
    for (int h=0;h<8;++h){ acc[2*h]+=bf2f((ushort)(uu[h]&0xffffu)); acc[2*h+1]+=bf2f((ushort)(uu[h]>>16)); }
  }
  __shared__ float red[4][64][16];
  #pragma unroll
  for (int c=0;c<16;++c) red[il][jl][c]=acc[c];
  __syncthreads();
  if (jl < 16){
    int c = jl;
    float t=0.f;
    for (int q=0;q<64;++q) t += red[il][q][c];
    g3[i*16+c] = t;
  }
}

// e-stream layer 0. g2a/g2b hold ROW-sums of the ee raw grid; the column sums
// the reference needs are sigma*rowsum (sigma = -1 on sin features).
__global__ __launch_bounds__(256) void k_e0(const float* __restrict__ kp, const float* __restrict__ g2a,
    const float* __restrict__ g2b, const float* __restrict__ g3, const float* __restrict__ W,
    const float* __restrict__ b, float* __restrict__ eout, float* __restrict__ g1out){
  int p = blockIdx.x*4 + (threadIdx.x>>6);
  int o = threadIdx.x & 63;
  float acc = b[o];
  #pragma unroll
  for (int d=0; d<3; ++d){
    acc = fmaf(kp[d], W[d*64+o] + W[(d+3)*64+o] + W[(d+6)*64+o], acc);
  }
  const float i512 = 1.f/512.f, i1024 = 1.f/1024.f;
  #pragma unroll
  for (int c=0;c<31;++c){
    float sg = (c!=0 && ((c-1)%6)>=3) ? -i512 : i512;
    acc = fmaf(g2a[p*31+c]*sg, W[(9+c)*64+o], acc);
  }
  #pragma unroll
  for (int c=0;c<31;++c){
    float sg = (c!=0 && ((c-1)%6)>=3) ? -i512 : i512;
    acc = fmaf(g2b[p*31+c]*sg, W[(40+c)*64+o], acc);
  }
  #pragma unroll
  for (int c=0;c<31;++c) acc = fmaf(g3[p*31+c]*i1024, W[(71+c)*64+o], acc);
  float v = ftanh(acc);
  eout[p*64+o] = v;
  atomicAdd(&g1out[(p<MH?0:64)+o], v);
}

// e-stream layers 1..3 (residual)
__global__ __launch_bounds__(256) void k_eupd(const float* __restrict__ eprev, float* __restrict__ eout,
    const float* __restrict__ W, const float* __restrict__ b, const float* __restrict__ g1in,
    const float* __restrict__ g2a, const float* __restrict__ g2b, const float* __restrict__ g3,
    float* __restrict__ g1out){
  int p = blockIdx.x*4 + (threadIdx.x>>6);
  int o = threadIdx.x & 63;
  const float i512 = 1.f/512.f, i1024 = 1.f/1024.f;
  float acc = b[o];
  #pragma unroll 8
  for (int c=0;c<64;++c) acc = fmaf(eprev[p*64+c], W[c*64+o], acc);
  #pragma unroll 8
  for (int c=0;c<64;++c) acc = fmaf(g1in[c]*i512, W[(64+c)*64+o], acc);
  #pragma unroll 8
  for (int c=0;c<64;++c) acc = fmaf(g1in[64+c]*i512, W[(128+c)*64+o], acc);
  #pragma unroll
  for (int c=0;c<16;++c) acc = fmaf(g2a[p*16+c]*i512, W[(192+c)*64+o], acc);
  #pragma unroll
  for (int c=0;c<16;++c) acc = fmaf(g2b[p*16+c]*i512, W[(208+c)*64+o], acc);
  #pragma unroll
  for (int c=0;c<16;++c) acc = fmaf(g3[p*16+c]*i1024, W[(224+c)*64+o], acc);
  float v = ftanh(acc) + eprev[p*64+o];
  eout[p*64+o] = v;
  if (g1out) atomicAdd(&g1out[(p<MH?0:64)+o], v);
}

__global__ __launch_bounds__(256) void k_orbz(const float* __restrict__ e4, const float* __restrict__ Wre,
    const float* __restrict__ Wim, const float* __restrict__ bre, const float* __restrict__ bim,
    const float* __restrict__ bfw, const float* __restrict__ sx, float* __restrict__ ore,
    float* __restrict__ oim, float* __restrict__ z){
  int p = blockIdx.x*4 + (threadIdx.x>>6);
  int o = threadIdx.x & 63;
  float ar = bre[o], ai = bim[o];
  #pragma unroll 8
  for (int a=0;a<64;++a){ float ev = e4[p*64+a]; ar = fmaf(ev, Wre[a*64+o], ar); ai = fmaf(ev, Wim[a*64+o], ai); }
  ore[p*64+o]=ar; oim[p*64+o]=ai;
  if (o<3){
    float zz = sx[(M1+p)*3+o];
    for (int a=0;a<64;++a) zz = fmaf(e4[p*64+a], bfw[a*3+o], zz);
    z[p*3+o]=zz;
  }
}

// fdet MLP: parallelized over 8 blocks (hs recomputed per block)
__global__ __launch_bounds__(256) void k_fdet(const float* __restrict__ kp, const float* __restrict__ w1,
    const float* __restrict__ b1, const float* __restrict__ w2, const float* __restrict__ b2,
    float* __restrict__ fdet){
  __shared__ float hs[64];
  int tid = threadIdx.x;
  if (tid < 64){
    float acc = b1[tid];
    for (int d=0;d<3;++d) acc = fmaf(kp[d], w1[d*64+tid], acc);
    hs[tid] = ftanh(acc);
  }
  __syncthreads();
  int c = blockIdx.x*256 + tid;
  if (c < 2044){
    float acc = b2[c];
    #pragma unroll 8
    for (int o=0;o<64;++o) acc = fmaf(hs[o], w2[o*2044+c], acc);
    float sp = (acc > 20.f) ? acc : log1pf(__expf(acc));
    int kk = c / 511, idx = c % 511;
    fdet[kk*512 + 1 + idx] = sp;
  }
  if (blockIdx.x == 0 && tid < 4) fdet[tid*512] = 1.f;
}

// D_up / D_dn plane waves
__global__ __launch_bounds__(256) void k_uv(const float* __restrict__ kp, const float* __restrict__ z,
                                            float2* __restrict__ U, float2* __restrict__ V){
  int gid = blockIdx.x*256 + threadIdx.x;
  int sel = gid >> 18;
  int rem = gid & 262143;
  int a = rem >> 9;
  int col = rem & 511;
  const float nrm = 0.031622776601683794f;  // L^{-3/2}
  const float* kr = kp + (sel ? (512+a)*3 : a*3);
  const float* zr = z + (sel ? (512+col)*3 : col*3);
  float th = kr[0]*zr[0] + kr[1]*zr[1] + kr[2]*zr[2];
  float s, c; __sincosf(th, &s, &c);
  float2 v = make_float2(nrm*c, nrm*s);
  if (sel) V[a*512+col] = v; else U[a*512+col] = v;
}

// T[k][i][b] = sum_a orb_up[i][a] * wdet[k][a][b]  (complex x real)
__global__ __launch_bounds__(256) void k_T(const float* __restrict__ ore, const float* __restrict__ oim,
                                           const float* __restrict__ wdet, float2* __restrict__ T){
  int k = blockIdx.x >> 7;
  int iblk = blockIdx.x & 127;
  int i = iblk*4 + (threadIdx.x>>6);
  int bc = threadIdx.x & 63;
  __shared__ float wd[4096];
  for (int t = threadIdx.x; t < 4096; t += 256) wd[t] = wdet[k*4096 + t];
  __syncthreads();
  float ar=0.f, ai=0.f;
  #pragma unroll 8
  for (int a=0;a<64;++a){
    float w = wd[a*64+bc];
    ar = fmaf(ore[i*64+a], w, ar);
    ai = fmaf(oim[i*64+a], w, ai);
  }
  T[((size_t)k*512 + i)*64 + bc] = make_float2(ar, ai);
}

// M[k][i][j] = (sum_a fdet[k][a] U[a][i] conj(V[a][j])) * (1 + sum_b T[k][i][b] orb_dn[j][b])
__global__ __launch_bounds__(256) void k_M(const float2* __restrict__ U, const float2* __restrict__ V,
    const float* __restrict__ fdet, const float2* __restrict__ T, const float* __restrict__ ore,
    const float* __restrict__ oim, float2* __restrict__ Mb){
  __shared__ float2 sm[4160];
  int k = blockIdx.x >> 8;
  int ty = (blockIdx.x >> 4) & 15;
  int tx = blockIdx.x & 15;
  int ib = ty*32, jb = tx*32;
  int i0 = (threadIdx.x >> 4)*2;
  int j0 = (threadIdx.x & 15)*2;
  const float* fk = fdet + k*512;
  float2 a00={0,0},a01={0,0},a10={0,0},a11={0,0};
  float2* As = sm;
  float2* Bs = sm + 512;
  for (int a0=0; a0<512; a0+=16){
    for (int t = threadIdx.x; t < 512; t += 256){
      int aa = t >> 5, il = t & 31;
      int a = a0 + aa;
      float fv = fk[a];
      float2 u = U[a*512 + ib + il];
      As[t] = make_float2(u.x*fv, u.y*fv);
      float2 v = V[a*512 + jb + il];
      Bs[t] = make_float2(v.x, -v.y);
    }
    __syncthreads();
    #pragma unroll
    for (int aa=0; aa<16; ++aa){
      float2 A0 = As[aa*32+i0], A1 = As[aa*32+i0+1];
      float2 B0 = Bs[aa*32+j0], B1 = Bs[aa*32+j0+1];
      cfma(a00,A0,B0); cfma(a01,A0,B1); cfma(a10,A1,B0); cfma(a11,A1,B1);
    }
    __syncthreads();
  }
  // phi phase
  float2* Ts = sm;         // [32][65]
  float2* Od = sm + 2080;  // [32][65]
  for (int t = threadIdx.x; t < 2048; t += 256){
    int il = t >> 6, bc = t & 63;
    Ts[il*65+bc] = T[((size_t)k*512 + ib + il)*64 + bc];
    int oidx = (512 + jb + il)*64 + bc;
    Od[il*65+bc] = make_float2(ore[oidx], oim[oidx]);
  }
  __syncthreads();
  float2 p00={1,0},p01={1,0},p10={1,0},p11={1,0};
  #pragma unroll 8
  for (int bb=0; bb<64; ++bb){
    float2 T0 = Ts[i0*65+bb], T1 = Ts[(i0+1)*65+bb];
    float2 O0 = Od[j0*65+bb], O1 = Od[(j0+1)*65+bb];
    cfma(p00,T0,O0); cfma(p01,T0,O1); cfma(p10,T1,O0); cfma(p11,T1,O1);
  }
  size_t base = ((size_t)k*512 + ib + i0)*512 + jb + j0;
  Mb[base]     = cmul(a00, p00);
  Mb[base+1]   = cmul(a01, p01);
  Mb[base+512] = cmul(a10, p10);
  Mb[base+513] = cmul(a11, p11);
}

// ---------------------------------------------------------------------------
// LU panel, nb=32, pivot candidates restricted to the 64 rows owned by
// wave 0 (det-invariant: any valid pivot sequence gives the same det with
// parity tracked). Phase 1: wave 0 factors its 64xNB subpanel entirely
// in-register with shfl-based argmax / broadcast / row-exchange — ZERO
// barriers. Phase 2 (one barrier): trailing rows do a fully parallel TRSM
// against U11 staged in LDS; rl<32 builds Linv = L11^{-1} for k_gemm.
// ---------------------------------------------------------------------------
__global__ __launch_bounds__(512)
void k_panel(float2* __restrict__ Mb, float2* __restrict__ LinvG,
             int* __restrict__ rowmap, int* __restrict__ swapc, int col0){
  int k = blockIdx.x;
  float2* Mk = Mb + (size_t)k*512*512;
  int R = 512 - col0;
  int R64 = R < 64 ? R : 64;      // pivot-candidate rows (wave 0)
  int rl = threadIdx.x;
  bool active = rl < R;
  int wv = rl >> 6;
  __shared__ int rm[64];
  __shared__ float2 Us[NB*33];
  __shared__ float2 dinv[NB];
  __shared__ float2 Ls[NB*NB];
  __shared__ float2 Yv[NB*NB];
  int prm = active ? rowmap[k*512 + col0 + rl] : 0;
  if (rl < 64 && active) rm[rl] = prm;
  float2 X[NB];
  if (active){
    const float4* rp = (const float4*)(Mk + (size_t)prm*512 + col0);
    #pragma unroll
    for (int q=0;q<NB/2;++q){ float4 v = rp[q]; X[2*q]=make_float2(v.x,v.y); X[2*q+1]=make_float2(v.z,v.w); }
  } else {
    #pragma unroll
    for (int j=0;j<NB;++j) X[j] = make_float2(0.f,0.f);
  }
  if (wv == 0){
    float2 curv = X[0];
    int sw = 0;
    for (int cc=0; cc<NB; ++cc){
      // intra-wave argmax over candidate rows [cc, R64)
      float val = (rl >= cc && rl < R64) ? fmaf(curv.x,curv.x,curv.y*curv.y) : -1.f;
      int idx = rl;
      #pragma unroll
      for (int off=32; off>0; off>>=1){
        float ov = __shfl_xor(val, off);
        int   oi = __shfl_xor(idx, off);
        if (ov > val || (ov == val && oi < idx)){ val = ov; idx = oi; }
      }
      int p = idx;                    // uniform across wave
      bool swp = (p != cc);
      if (swp){ sw++; if (rl == 0){ int a=rm[cc]; rm[cc]=rm[p]; rm[p]=a; } }
      float2 dg = shfl2(X[cc], p);    // pivot diagonal (post-exchange row cc)
      float dn = 1.f/fmaf(dg.x,dg.x,dg.y*dg.y);
      float2 inv = make_float2(dg.x*dn, -dg.y*dn);
      float2 oldcc = shfl2(X[cc], cc);
      float2 myc = (swp && rl == p) ? oldcc : curv;   // my value at column cc after exchange
      float2 l = cmul(myc, inv);
      if (swp){
        #pragma unroll
        for (int j=0;j<NB;++j){
          float2 pr = shfl2(X[j], p);
          float2 oc = shfl2(X[j], cc);
          float2 xj = X[j];
          if (rl == cc) xj = pr;
          else if (rl == p) xj = oc;
          if (rl > cc){
            if (j > cc){
              xj.x = fmaf(-l.x, pr.x, fmaf( l.y, pr.y, xj.x));
              xj.y = fmaf(-l.x, pr.y, fmaf(-l.y, pr.x, xj.y));
            } else if (j == cc) xj = l;
          }
          X[j] = xj;
          if (j == cc+1 && rl > cc) curv = xj;
          if (j == cc+1 && rl == cc) curv = xj;
        }
      } else {
        #pragma unroll
        for (int j=0;j<NB;++j){
          float2 pr = shfl2(X[j], p);
          float2 xj = X[j];
          if (rl > cc){
            if (j > cc){
              xj.x = fmaf(-l.x, pr.x, fmaf( l.y, pr.y, xj.x));
              xj.y = fmaf(-l.x, pr.y, fmaf(-l.y, pr.x, xj.y));
            } else if (j == cc) xj = l;
          }
          X[j] = xj;
          if (j == cc+1) curv = xj;
        }
      }
    }
    // writeback factored subpanel + rowmap; stage U11 / Ls / dinv
    if (rl < R64){
      float4* wp = (float4*)(Mk + (size_t)rm[rl]*512 + col0);
      #pragma unroll
      for (int q=0;q<NB/2;++q) wp[q] = make_float4(X[2*q].x,X[2*q].y,X[2*q+1].x,X[2*q+1].y);
      rowmap[k*512 + col0 + rl] = rm[rl];
    }
    if (rl < NB){
      #pragma unroll
      for (int j=0;j<NB;++j){
        Us[rl*33+j] = X[j];
        float2 v;
        if      (j <  rl) v = X[j];
        else if (j == rl) v = make_float2(1.f,0.f);
        else              v = make_float2(0.f,0.f);
        Ls[rl*NB+j] = v;
      }
      float2 d = X[rl];
      float dn = 1.f/fmaf(d.x,d.x,d.y*d.y);
      dinv[rl] = make_float2(d.x*dn, -d.y*dn);
    }
    if (rl == 0) swapc[k] += sw;
  }
  __syncthreads();
  // trailing rows: TRSM x·U11 = a  (row-wise forward substitution)
  if (rl >= 64 && active){
    #pragma unroll
    for (int j=0;j<NB;++j){
      float2 t = X[j];
      #pragma unroll
      for (int q=0;q<NB;++q){
        if (q < j){
          float2 u = Us[q*33+j];
          t.x = fmaf(-X[q].x, u.x, fmaf( X[q].y, u.y, t.x));
          t.y = fmaf(-X[q].x, u.y, fmaf(-X[q].y, u.x, t.y));
        }
      }
      X[j] = cmul(t, dinv[j]);
    }
    float4* wp = (float4*)(Mk + (size_t)prm*512 + col0);
    #pragma unroll
    for (int q=0;q<NB/2;++q) wp[q] = make_float4(X[2*q].x,X[2*q].y,X[2*q+1].x,X[2*q+1].y);
  }
  // Linv = L11^{-1} (threads 0..31, one wave, intra-wave LDS ordering)
  if (rl < NB){
    for (int i=0;i<NB;++i){
      float2 acc = (i==rl)? make_float2(1.f,0.f) : make_float2(0.f,0.f);
      for (int q=rl; q<i; ++q){
        float2 lv = Ls[i*NB+q];
        float2 yv = Yv[q*NB+rl];
        acc.x = fmaf(-lv.x, yv.x, fmaf( lv.y, yv.y, acc.x));
        acc.y = fmaf(-lv.x, yv.y, fmaf(-lv.y, yv.x, acc.y));
      }
      Yv[i*NB+rl] = acc;
    }
  }
  __syncthreads();
  {
    float4* dst = (float4*)(LinvG + (size_t)k*(NB*NB));
    const float4* src = (const float4*)Yv;
    for (int q=rl; q<NB*NB/2; q+=blockDim.x) dst[q] = src[q];
  }
}

// trailing update with fused TRSM: Bs = Linv @ A12 computed on the fly
// (U12 is never materialized). A22 -= L21 @ Bs (K=32), 32x32 tiles.
__global__ __launch_bounds__(256) void k_gemm(float2* __restrict__ Mb, const float2* __restrict__ LinvG,
                                              const int* __restrict__ rowmap, int col0){
  int k = blockIdx.z;
  float2* Mk = Mb + (size_t)k*512*512;
  int e0 = col0 + NB;
  int r0 = e0 + blockIdx.x*32;
  int j0c = e0 + blockIdx.y*32;
  int tid = threadIdx.x;
  int jl = tid & 31, rg = tid >> 5;
  __shared__ float2 As[NB*33];
  __shared__ float2 Bs[NB*33];
  __shared__ float2 Av[NB*33];
  __shared__ float2 Li[NB*NB];
  __shared__ int prA[32];
  __shared__ int prB[NB];
  if (tid < 32) prA[tid] = rowmap[k*512 + r0 + tid];
  else if (tid < 64) prB[tid-32] = rowmap[k*512 + col0 + (tid-32)];
  {
    const float4* src = (const float4*)(LinvG + (size_t)k*(NB*NB));
    float4* dst = (float4*)Li;
    for (int q=tid; q<NB*NB/2; q+=256) dst[q] = src[q];
  }
  __syncthreads();
  #pragma unroll
  for (int s=0;s<4;++s){
    int a = rg + 8*s;
    Av[a*33 + jl] = Mk[(size_t)prB[a]*512 + j0c + jl];
  }
  for (int t=tid; t<1024; t+=256){
    int rl = t >> 5, kk = t & 31;
    As[kk*33+rl] = Mk[(size_t)prA[rl]*512 + col0 + kk];
  }
  __syncthreads();
  #pragma unroll
  for (int s=0;s<4;++s){
    int m = rg + 8*s;
    float2 acc = make_float2(0.f,0.f);
    #pragma unroll 8
    for (int a=0;a<NB;++a) cfma(acc, Li[m*NB+a], Av[a*33+jl]);
    Bs[m*33+jl] = acc;
  }
  __syncthreads();
  int i0 = (tid >> 4)*2, j0 = (tid & 15)*2;
  float2 a00={0,0},a01={0,0},a10={0,0},a11={0,0};
  #pragma unroll 16
  for (int kk=0;kk<NB;++kk){
    float2 A0 = As[kk*33+i0], A1 = As[kk*33+i0+1];
    float2 B0 = Bs[kk*33+j0], B1 = Bs[kk*33+j0+1];
    cfma(a00,A0,B0); cfma(a01,A0,B1); cfma(a10,A1,B0); cfma(a11,A1,B1);
  }
  size_t ro0 = (size_t)prA[i0]*512 + j0c + j0;
  size_t ro1 = (size_t)prA[i0+1]*512 + j0c + j0;
  float2 c0 = Mk[ro0];   c0.x-=a00.x; c0.y-=a00.y; Mk[ro0]=c0;
  float2 c1 = Mk[ro0+1]; c1.x-=a01.x; c1.y-=a01.y; Mk[ro0+1]=c1;
  float2 c2 = Mk[ro1];   c2.x-=a10.x; c2.y-=a10.y; Mk[ro1]=c2;
  float2 c3 = Mk[ro1+1]; c3.x-=a11.x; c3.y-=a11.y; Mk[ro1+1]=c3;
}

// final: logabs/phase per k from U diag (via rowmap) + swap parity; log-sum-exp combine
__global__ void k_det(const float2* __restrict__ Mb, const int* __restrict__ rowmap,
                      const int* __restrict__ swapc, float* __restrict__ out, int out_size){
  int tid = threadIdx.x;
  int k = tid >> 6, lane = tid & 63;
  const float2* Mk = Mb + (size_t)k*512*512;
  double la = 0.0, ang = 0.0;
  for (int q=0;q<8;++q){
    int i = lane*8 + q;
    int pr = rowmap[k*512 + i];
    float2 u = Mk[(size_t)pr*512+i];
    double re = (double)u.x, im = (double)u.y;
    la += 0.5*log(re*re + im*im);
    ang += atan2(im, re);
  }
  #pragma unroll
  for (int off=32; off>0; off>>=1){
    la += __shfl_down(la, off);
    ang += __shfl_down(ang, off);
  }
  __shared__ double las[4], angs[4];
  if (lane==0){
    las[k] = la;
    angs[k] = ang + 3.14159265358979323846*(double)(swapc[k] & 1);
  }
  __syncthreads();
  if (tid==0){
    double mx = las[0];
    for (int q=1;q<4;++q) mx = fmax(mx, las[q]);
    double sre=0.0, sim=0.0;
    for (int q=0;q<4;++q){
      double w = exp(las[q]-mx);
      sre += w*cos(angs[q]);
      sim += w*sin(angs[q]);
    }
    double mag = sqrt(sre*sre+sim*sim);
    out[0] = (float)(log(mag)+mx);
    if (out_size > 1) out[1] = (float)atan2(sim, sre);
    for (int q=2;q<out_size;++q) out[q] = 0.f;
  }
}

extern "C" void kernel_launch(void* const* d_in, const int* in_sizes, int n_in,
                              void* d_out, int out_size, void* d_ws, size_t ws_size,
                              hipStream_t stream){
  const float* sx   = (const float*)d_in[0];
  const float* kp   = (const float*)d_in[1];
  const float* we0  = (const float*)d_in[2];
  const float* be0  = (const float*)d_in[3];
  const float* weR  = (const float*)d_in[4];
  const float* beR  = (const float*)d_in[5];
  const float* wee0 = (const float*)d_in[6];
  const float* bee0 = (const float*)d_in[7];
  const float* weeR = (const float*)d_in[8];
  const float* beeR = (const float*)d_in[9];
  const float* wep0 = (const float*)d_in[10];
  const float* bep0 = (const float*)d_in[11];
  const float* wepR = (const float*)d_in[12];
  const float* bepR = (const float*)d_in[13];
  const float* owre = (const float*)d_in[14];
  const float* owim = (const float*)d_in[15];
  const float* obre = (const float*)d_in[16];
  const float* obim = (const float*)d_in[17];
  const float* wdet = (const float*)d_in[18];
  const float* bfw  = (const float*)d_in[19];
  const float* mw1  = (const float*)d_in[20];
  const float* mb1  = (const float*)d_in[21];
  const float* mw2  = (const float*)d_in[22];
  const float* mb2  = (const float*)d_in[23];

  char* ws = (char*)d_ws;
  size_t off = 0;
  auto alloc = [&](size_t bytes)->char*{
    char* p = ws + off;
    off = (off + bytes + 255) & ~(size_t)255;
    return p;
  };
  ushort* ee   = (ushort*)alloc(33554432);
  ushort* ep   = (ushort*)alloc(33554432);
  float2* Mb   = (float2*)alloc(8388608);
  float2* U    = (float2*)alloc(2097152);
  float2* V    = (float2*)alloc(2097152);
  float2* T    = (float2*)alloc(1048576);
  float*  eS   = (float*)alloc(1048576);
  float*  ore  = (float*)alloc(262144);
  float*  oim  = (float*)alloc(262144);
  float*  z    = (float*)alloc(12288);
  float*  fdet = (float*)alloc(8192);
  float2* Linv = (float2*)alloc(131072);
  int*    rowmap = (int*)alloc(8192);
  char*   zst  = ws + off;
  float*  g2a0 = (float*)alloc(126976);
  float*  g2b0 = (float*)alloc(126976);
  float*  g30  = (float*)alloc(126976);
  float*  geeA = (float*)alloc(196608);
  float*  geeB = (float*)alloc(196608);
  float*  gep  = (float*)alloc(196608);
  float*  g1s  = (float*)alloc(1536);
  int*    swpc = (int*)alloc(16);
  int zn = (int)(((char*)(swpc+4) - zst)/4);

  float* e1 = eS;           float* e2 = eS + 65536;
  float* e3 = eS + 131072;  float* e4 = eS + 196608;
  float* geeA1 = geeA;      float* geeA2 = geeA+16384; float* geeA3 = geeA+32768;
  float* geeB1 = geeB;      float* geeB2 = geeB+16384; float* geeB3 = geeB+32768;
  float* gep1  = gep;       float* gep2  = gep+16384;  float* gep3  = gep+32768;
  float* g1s1 = g1s; float* g1s2 = g1s+128; float* g1s3 = g1s+256;

  k_zero<<<256,256,0,stream>>>((float*)zst, zn);
  k_iota<<<8,256,0,stream>>>(rowmap);
  k_pair0<<<4096,256,0,stream>>>(sx, wee0, bee0, ee, 1, g2a0, g2b0);
  k_pair0<<<4096,256,0,stream>>>(sx, wep0, bep0, ep, 0, g30, g30);
  k_e0<<<256,256,0,stream>>>(kp, g2a0, g2b0, g30, we0, be0, e1, g1s1);
  k_gee<<<128,256,0,stream>>>(ee, geeA1, geeB1);
  k_gep<<<256,256,0,stream>>>(ep, gep1);
  k_eupd<<<256,256,0,stream>>>(e1, e2, weR, beR, g1s1, geeA1, geeB1, gep1, g1s2);
  k_pairU<<<4096,256,0,stream>>>(ee, weeR, beeR);
  k_pairU<<<4096,256,0,stream>>>(ep, wepR, bepR);
  k_gee<<<128,256,0,stream>>>(ee, geeA2, geeB2);
  k_gep<<<256,256,0,stream>>>(ep, gep2);
  k_eupd<<<256,256,0,stream>>>(e2, e3, weR+240*64, beR+64, g1s2, geeA2, geeB2, gep2, g1s3);
  k_pairU<<<4096,256,0,stream>>>(ee, weeR+256, beeR+16);
  k_pairU<<<4096,256,0,stream>>>(ep, wepR+256, bepR+16);
  k_gee<<<128,256,0,stream>>>(ee, geeA3, geeB3);
  k_gep<<<256,256,0,stream>>>(ep, gep3);
  k_eupd<<<256,256,0,stream>>>(e3, e4, weR+2*240*64, beR+128, g1s3, geeA3, geeB3, gep3, nullptr);
  k_orbz<<<256,256,0,stream>>>(e4, owre, owim, obre, obim, bfw, sx, ore, oim, z);
  k_fdet<<<8,256,0,stream>>>(kp, mw1, mb1, mw2, mb2, fdet);
  k_uv<<<2048,256,0,stream>>>(kp, z, U, V);
  k_T<<<512,256,0,stream>>>(ore, oim, wdet, T);
  k_M<<<1024,256,0,stream>>>(U, V, fdet, T, ore, oim, Mb);
  for (int tpan=0;tpan<16;++tpan){
    int col0 = tpan*NB;
    int R = 512 - col0;
    int Rpad = (R + 63) & ~63;
    k_panel<<<4, Rpad, 0, stream>>>(Mb, Linv, rowmap, swpc, col0);
    if (tpan < 15){
      int nch = 15 - tpan;
      k_gemm<<<dim3(nch,nch,4),256,0,stream>>>(Mb, Linv, rowmap, col0);
    }
  }
  k_det<<<1,256,0,stream>>>(Mb, rowmap, swpc, (float*)d_out, out_size);
  (void)in_sizes; (void)n_in; (void)ws_size;
}

// Round 11
// 1842.890 us; speedup vs baseline: 2.0166x; 2.0166x over previous
//
#include <hip/hip_runtime.h>

typedef unsigned int uint;
typedef unsigned short ushort;

#define M1 1024
#define MH 512
#define PI_F 3.14159265358979323846f
#define LBOX 10.0f
#define NB 32

__device__ __forceinline__ float bf2f(ushort h){ return __uint_as_float(((uint)h)<<16); }
__device__ __forceinline__ ushort f2bf(float f){ uint u = __float_as_uint(f); uint r = (u + 0x7fffu + ((u>>16)&1u))>>16; return (ushort)r; }
__device__ __forceinline__ float ftanh(float x){ float e = __expf(2.f*x); return 1.f - 2.f/(e+1.f); }
__device__ __forceinline__ float2 cmul(float2 a, float2 b){ return make_float2(a.x*b.x - a.y*b.y, a.x*b.y + a.y*b.x); }
__device__ __forceinline__ void cfma(float2& c, float2 a, float2 b){
  c.x = fmaf(a.x,b.x,fmaf(-a.y,b.y,c.x));
  c.y = fmaf(a.x,b.y,fmaf(a.y,b.x,c.y));
}

// 31 Fourier features: [r, cos(k=1,d0..2), sin(k=1,d0..2), ..., k=5]
__device__ __forceinline__ void fourier31(float d0, float d1, float d2, bool diag, float f[31]){
  const float k1 = PI_F / LBOX;
  float s[3], c[3];
  __sincosf(k1*d0, &s[0], &c[0]);
  __sincosf(k1*d1, &s[1], &c[1]);
  __sincosf(k1*d2, &s[2], &c[2]);
  float r = diag ? 0.f : (LBOX/PI_F)*sqrtf(s[0]*s[0]+s[1]*s[1]+s[2]*s[2]);
  f[0] = r;
  float cb[3], sb[3], cc[3], sc[3];
  #pragma unroll
  for (int d=0; d<3; ++d){ cb[d] = 1.f - 2.f*s[d]*s[d]; sb[d] = 2.f*s[d]*c[d]; cc[d]=cb[d]; sc[d]=sb[d]; }
  #pragma unroll
  for (int k=0;k<5;++k){
    #pragma unroll
    for (int d=0; d<3; ++d){ f[1+6*k+d] = cc[d]; f[4+6*k+d] = sc[d]; }
    if (k<4){
      #pragma unroll
      for (int d=0; d<3; ++d){
        float nc = cc[d]*cb[d]-sc[d]*sb[d];
        float ns = sc[d]*cb[d]+cc[d]*sb[d];
        cc[d]=nc; sc[d]=ns;
      }
    }
  }
}

__global__ void k_zero(float* __restrict__ p, int n){
  int i = blockIdx.x*256 + threadIdx.x;
  int st = gridDim.x*256;
  for (; i<n; i+=st) p[i] = 0.f;
}

__global__ void k_iota(int* __restrict__ rowmap){
  int q = blockIdx.x*256 + threadIdx.x;
  rowmap[q] = q & 511;
}

// layer-0: fourier feats -> tanh(f @ W31x16 + b), store bf16 [i][j][16].
// FUSED: also block-reduces the 31 raw features and atomically accumulates
// row-sums (see k_e0 for the symmetry-based column-sum recovery).
__global__ __launch_bounds__(256) void k_pair0(const float* __restrict__ sx, const float* __restrict__ W,
                                               const float* __restrict__ b, ushort* __restrict__ out, int is_ee,
                                               float* __restrict__ gA, float* __restrict__ gB){
  int bx = blockIdx.x;
  int i = bx >> 2;
  int chunk = bx & 3;
  int j = (chunk << 8) + threadIdx.x;
  const float* xs = sx + 3*M1;
  float xi0 = xs[3*i], xi1 = xs[3*i+1], xi2 = xs[3*i+2];
  const float* oth = is_ee ? xs : sx;
  float y0 = oth[3*j], y1 = oth[3*j+1], y2 = oth[3*j+2];
  float f[31];
  fourier31(xi0-y0, xi1-y1, xi2-y2, is_ee && (i==j), f);
  float acc[16];
  #pragma unroll
  for (int o=0;o<16;++o) acc[o] = b[o];
  #pragma unroll
  for (int c=0;c<31;++c){ float fv = f[c];
    #pragma unroll
    for (int o=0;o<16;++o) acc[o] = fmaf(fv, W[c*16+o], acc[o]);
  }
  uint u[8];
  #pragma unroll
  for (int h=0;h<8;++h){
    ushort lo = f2bf(ftanh(acc[2*h]));
    ushort hi = f2bf(ftanh(acc[2*h+1]));
    u[h] = (uint)lo | ((uint)hi<<16);
  }
  uint4* dst = (uint4*)(out + ((size_t)i*M1 + j)*16);
  dst[0] = make_uint4(u[0],u[1],u[2],u[3]);
  dst[1] = make_uint4(u[4],u[5],u[6],u[7]);
  // block tree-reduction of the 31 raw features over 256 threads
  __shared__ float buf[256*33];
  #pragma unroll
  for (int c=0;c<31;++c) buf[threadIdx.x*33+c] = f[c];
  __syncthreads();
  #pragma unroll
  for (int s=128; s>0; s>>=1){
    if (threadIdx.x < s){
      #pragma unroll
      for (int c=0;c<31;++c) buf[threadIdx.x*33+c] += buf[(threadIdx.x+s)*33+c];
    }
    __syncthreads();
  }
  if (threadIdx.x < 31){
    float* g = (is_ee && chunk >= 2) ? gB : gA;
    atomicAdd(&g[i*31+threadIdx.x], buf[threadIdx.x]);
  }
}

// layers 1..2: in-place ten = tanh(ten @ W16x16 + b) + ten
__global__ __launch_bounds__(256) void k_pairU(ushort* __restrict__ ten, const float* __restrict__ W,
                                               const float* __restrict__ b){
  size_t base = ((size_t)blockIdx.x*256 + threadIdx.x)*16;
  uint4 a0 = ((uint4*)(ten+base))[0];
  uint4 a1 = ((uint4*)(ten+base))[1];
  uint uu[8] = {a0.x,a0.y,a0.z,a0.w,a1.x,a1.y,a1.z,a1.w};
  float v[16];
  #pragma unroll
  for (int h=0;h<8;++h){ v[2*h] = bf2f((ushort)(uu[h]&0xffffu)); v[2*h+1] = bf2f((ushort)(uu[h]>>16)); }
  float acc[16];
  #pragma unroll
  for (int o=0;o<16;++o) acc[o] = b[o];
  #pragma unroll
  for (int c=0;c<16;++c){ float fv = v[c];
    #pragma unroll
    for (int o=0;o<16;++o) acc[o] = fmaf(fv, W[c*16+o], acc[o]);
  }
  uint w[8];
  #pragma unroll
  for (int h=0;h<8;++h){
    float q0 = ftanh(acc[2*h]) + v[2*h];
    float q1 = ftanh(acc[2*h+1]) + v[2*h+1];
    w[h] = (uint)f2bf(q0) | ((uint)f2bf(q1)<<16);
  }
  ((uint4*)(ten+base))[0] = make_uint4(w[0],w[1],w[2],w[3]);
  ((uint4*)(ten+base))[1] = make_uint4(w[4],w[5],w[6],w[7]);
}

// half-column means of a bf16 [1024][1024][16] tensor (sum over i<512 -> gA, i>=512 -> gB), atomic
__global__ __launch_bounds__(256) void k_gee(const ushort* __restrict__ ten, float* __restrict__ gA, float* __restrict__ gB){
  int jb = blockIdx.x >> 3;
  int ic = blockIdx.x & 7;
  int jl = threadIdx.x & 63;
  int iq = threadIdx.x >> 6;
  int j = jb*64 + jl;
  float acc[16];
  #pragma unroll
  for (int c=0;c<16;++c) acc[c]=0.f;
  for (int s=0;s<32;++s){
    int i = ic*128 + iq + 4*s;
    const uint4* src = (const uint4*)(ten + ((size_t)i*M1 + j)*16);
    uint4 a0 = src[0], a1 = src[1];
    uint uu[8]={a0.x,a0.y,a0.z,a0.w,a1.x,a1.y,a1.z,a1.w};
    #pragma unroll
    for (int h=0;h<8;++h){ acc[2*h]+=bf2f((ushort)(uu[h]&0xffffu)); acc[2*h+1]+=bf2f((ushort)(uu[h]>>16)); }
  }
  __shared__ float red[4][64][16];
  #pragma unroll
  for (int c=0;c<16;++c) red[iq][jl][c]=acc[c];
  __syncthreads();
  if (iq==0){
    float* out = (ic<4)? gA : gB;
    #pragma unroll
    for (int c=0;c<16;++c){
      float t = red[0][jl][c]+red[1][jl][c]+red[2][jl][c]+red[3][jl][c];
      atomicAdd(&out[j*16+c], t);
    }
  }
}

// row means of bf16 tensor (sum over j) -> direct write
__global__ __launch_bounds__(256) void k_gep(const ushort* __restrict__ ten, float* __restrict__ g3){
  int ib = blockIdx.x;
  int il = threadIdx.x >> 6;
  int jl = threadIdx.x & 63;
  int i = ib*4 + il;
  float acc[16];
  #pragma unroll
  for (int c=0;c<16;++c) acc[c]=0.f;
  for (int s=0;s<16;++s){
    int j = jl + 64*s;
    const uint4* src = (const uint4*)(ten + ((size_t)i*M1 + j)*16);
    uint4 a0 = src[0], a1 = src[1];
    uint uu[8]={a0.x,a0.y,a0.z,a0.w,a1.x,a1.y,a1.z,a1.w};
    #pragma unroll
    for (int h=0;h<8;++h){ acc[2*h]+=bf2f((ushort)(uu[h]&0xffffu)); acc[2*h+1]+=bf2f((ushort)(uu[h]>>16)); }
  }
  __shared__ float red[4][64][16];
  #pragma unroll
  for (int c=0;c<16;++c) red[il][jl][c]=acc[c];
  __syncthreads();
  if (jl < 16){
    int c = jl;
    float t=0.f;
    for (int q=0;q<64;++q) t += red[il][q][c];
    g3[i*16+c] = t;
  }
}

// e-stream layer 0. g2a/g2b hold ROW-sums of the ee raw grid; the column sums
// the reference needs are sigma*rowsum (sigma = -1 on sin features).
__global__ __launch_bounds__(256) void k_e0(const float* __restrict__ kp, const float* __restrict__ g2a,
    const float* __restrict__ g2b, const float* __restrict__ g3, const float* __restrict__ W,
    const float* __restrict__ b, float* __restrict__ eout, float* __restrict__ g1out){
  int p = blockIdx.x*4 + (threadIdx.x>>6);
  int o = threadIdx.x & 63;
  float acc = b[o];
  #pragma unroll
  for (int d=0; d<3; ++d){
    acc = fmaf(kp[d], W[d*64+o] + W[(d+3)*64+o] + W[(d+6)*64+o], acc);
  }
  const float i512 = 1.f/512.f, i1024 = 1.f/1024.f;
  #pragma unroll
  for (int c=0;c<31;++c){
    float sg = (c!=0 && ((c-1)%6)>=3) ? -i512 : i512;
    acc = fmaf(g2a[p*31+c]*sg, W[(9+c)*64+o], acc);
  }
  #pragma unroll
  for (int c=0;c<31;++c){
    float sg = (c!=0 && ((c-1)%6)>=3) ? -i512 : i512;
    acc = fmaf(g2b[p*31+c]*sg, W[(40+c)*64+o], acc);
  }
  #pragma unroll
  for (int c=0;c<31;++c) acc = fmaf(g3[p*31+c]*i1024, W[(71+c)*64+o], acc);
  float v = ftanh(acc);
  eout[p*64+o] = v;
  atomicAdd(&g1out[(p<MH?0:64)+o], v);
}

// e-stream layers 1..3 (residual)
__global__ __launch_bounds__(256) void k_eupd(const float* __restrict__ eprev, float* __restrict__ eout,
    const float* __restrict__ W, const float* __restrict__ b, const float* __restrict__ g1in,
    const float* __restrict__ g2a, const float* __restrict__ g2b, const float* __restrict__ g3,
    float* __restrict__ g1out){
  int p = blockIdx.x*4 + (threadIdx.x>>6);
  int o = threadIdx.x & 63;
  const float i512 = 1.f/512.f, i1024 = 1.f/1024.f;
  float acc = b[o];
  #pragma unroll 8
  for (int c=0;c<64;++c) acc = fmaf(eprev[p*64+c], W[c*64+o], acc);
  #pragma unroll 8
  for (int c=0;c<64;++c) acc = fmaf(g1in[c]*i512, W[(64+c)*64+o], acc);
  #pragma unroll 8
  for (int c=0;c<64;++c) acc = fmaf(g1in[64+c]*i512, W[(128+c)*64+o], acc);
  #pragma unroll
  for (int c=0;c<16;++c) acc = fmaf(g2a[p*16+c]*i512, W[(192+c)*64+o], acc);
  #pragma unroll
  for (int c=0;c<16;++c) acc = fmaf(g2b[p*16+c]*i512, W[(208+c)*64+o], acc);
  #pragma unroll
  for (int c=0;c<16;++c) acc = fmaf(g3[p*16+c]*i1024, W[(224+c)*64+o], acc);
  float v = ftanh(acc) + eprev[p*64+o];
  eout[p*64+o] = v;
  if (g1out) atomicAdd(&g1out[(p<MH?0:64)+o], v);
}

__global__ __launch_bounds__(256) void k_orbz(const float* __restrict__ e4, const float* __restrict__ Wre,
    const float* __restrict__ Wim, const float* __restrict__ bre, const float* __restrict__ bim,
    const float* __restrict__ bfw, const float* __restrict__ sx, float* __restrict__ ore,
    float* __restrict__ oim, float* __restrict__ z){
  int p = blockIdx.x*4 + (threadIdx.x>>6);
  int o = threadIdx.x & 63;
  float ar = bre[o], ai = bim[o];
  #pragma unroll 8
  for (int a=0;a<64;++a){ float ev = e4[p*64+a]; ar = fmaf(ev, Wre[a*64+o], ar); ai = fmaf(ev, Wim[a*64+o], ai); }
  ore[p*64+o]=ar; oim[p*64+o]=ai;
  if (o<3){
    float zz = sx[(M1+p)*3+o];
    for (int a=0;a<64;++a) zz = fmaf(e4[p*64+a], bfw[a*3+o], zz);
    z[p*3+o]=zz;
  }
}

// fdet MLP: parallelized over 8 blocks (hs recomputed per block)
__global__ __launch_bounds__(256) void k_fdet(const float* __restrict__ kp, const float* __restrict__ w1,
    const float* __restrict__ b1, const float* __restrict__ w2, const float* __restrict__ b2,
    float* __restrict__ fdet){
  __shared__ float hs[64];
  int tid = threadIdx.x;
  if (tid < 64){
    float acc = b1[tid];
    for (int d=0;d<3;++d) acc = fmaf(kp[d], w1[d*64+tid], acc);
    hs[tid] = ftanh(acc);
  }
  __syncthreads();
  int c = blockIdx.x*256 + tid;
  if (c < 2044){
    float acc = b2[c];
    #pragma unroll 8
    for (int o=0;o<64;++o) acc = fmaf(hs[o], w2[o*2044+c], acc);
    float sp = (acc > 20.f) ? acc : log1pf(__expf(acc));
    int kk = c / 511, idx = c % 511;
    fdet[kk*512 + 1 + idx] = sp;
  }
  if (blockIdx.x == 0 && tid < 4) fdet[tid*512] = 1.f;
}

// D_up / D_dn plane waves
__global__ __launch_bounds__(256) void k_uv(const float* __restrict__ kp, const float* __restrict__ z,
                                            float2* __restrict__ U, float2* __restrict__ V){
  int gid = blockIdx.x*256 + threadIdx.x;
  int sel = gid >> 18;
  int rem = gid & 262143;
  int a = rem >> 9;
  int col = rem & 511;
  const float nrm = 0.031622776601683794f;  // L^{-3/2}
  const float* kr = kp + (sel ? (512+a)*3 : a*3);
  const float* zr = z + (sel ? (512+col)*3 : col*3);
  float th = kr[0]*zr[0] + kr[1]*zr[1] + kr[2]*zr[2];
  float s, c; __sincosf(th, &s, &c);
  float2 v = make_float2(nrm*c, nrm*s);
  if (sel) V[a*512+col] = v; else U[a*512+col] = v;
}

// T[k][i][b] = sum_a orb_up[i][a] * wdet[k][a][b]  (complex x real)
__global__ __launch_bounds__(256) void k_T(const float* __restrict__ ore, const float* __restrict__ oim,
                                           const float* __restrict__ wdet, float2* __restrict__ T){
  int k = blockIdx.x >> 7;
  int iblk = blockIdx.x & 127;
  int i = iblk*4 + (threadIdx.x>>6);
  int bc = threadIdx.x & 63;
  __shared__ float wd[4096];
  for (int t = threadIdx.x; t < 4096; t += 256) wd[t] = wdet[k*4096 + t];
  __syncthreads();
  float ar=0.f, ai=0.f;
  #pragma unroll 8
  for (int a=0;a<64;++a){
    float w = wd[a*64+bc];
    ar = fmaf(ore[i*64+a], w, ar);
    ai = fmaf(oim[i*64+a], w, ai);
  }
  T[((size_t)k*512 + i)*64 + bc] = make_float2(ar, ai);
}

// M[k][i][j] = (sum_a fdet[k][a] U[a][i] conj(V[a][j])) * (1 + sum_b T[k][i][b] orb_dn[j][b])
__global__ __launch_bounds__(256) void k_M(const float2* __restrict__ U, const float2* __restrict__ V,
    const float* __restrict__ fdet, const float2* __restrict__ T, const float* __restrict__ ore,
    const float* __restrict__ oim, float2* __restrict__ Mb){
  __shared__ float2 sm[4160];
  int k = blockIdx.x >> 8;
  int ty = (blockIdx.x >> 4) & 15;
  int tx = blockIdx.x & 15;
  int ib = ty*32, jb = tx*32;
  int i0 = (threadIdx.x >> 4)*2;
  int j0 = (threadIdx.x & 15)*2;
  const float* fk = fdet + k*512;
  float2 a00={0,0},a01={0,0},a10={0,0},a11={0,0};
  float2* As = sm;
  float2* Bs = sm + 512;
  for (int a0=0; a0<512; a0+=16){
    for (int t = threadIdx.x; t < 512; t += 256){
      int aa = t >> 5, il = t & 31;
      int a = a0 + aa;
      float fv = fk[a];
      float2 u = U[a*512 + ib + il];
      As[t] = make_float2(u.x*fv, u.y*fv);
      float2 v = V[a*512 + jb + il];
      Bs[t] = make_float2(v.x, -v.y);
    }
    __syncthreads();
    #pragma unroll
    for (int aa=0; aa<16; ++aa){
      float2 A0 = As[aa*32+i0], A1 = As[aa*32+i0+1];
      float2 B0 = Bs[aa*32+j0], B1 = Bs[aa*32+j0+1];
      cfma(a00,A0,B0); cfma(a01,A0,B1); cfma(a10,A1,B0); cfma(a11,A1,B1);
    }
    __syncthreads();
  }
  // phi phase
  float2* Ts = sm;         // [32][65]
  float2* Od = sm + 2080;  // [32][65]
  for (int t = threadIdx.x; t < 2048; t += 256){
    int il = t >> 6, bc = t & 63;
    Ts[il*65+bc] = T[((size_t)k*512 + ib + il)*64 + bc];
    int oidx = (512 + jb + il)*64 + bc;
    Od[il*65+bc] = make_float2(ore[oidx], oim[oidx]);
  }
  __syncthreads();
  float2 p00={1,0},p01={1,0},p10={1,0},p11={1,0};
  #pragma unroll 8
  for (int bb=0; bb<64; ++bb){
    float2 T0 = Ts[i0*65+bb], T1 = Ts[(i0+1)*65+bb];
    float2 O0 = Od[j0*65+bb], O1 = Od[(j0+1)*65+bb];
    cfma(p00,T0,O0); cfma(p01,T0,O1); cfma(p10,T1,O0); cfma(p11,T1,O1);
  }
  size_t base = ((size_t)k*512 + ib + i0)*512 + jb + j0;
  Mb[base]     = cmul(a00, p00);
  Mb[base+1]   = cmul(a01, p01);
  Mb[base+512] = cmul(a10, p10);
  Mb[base+513] = cmul(a11, p11);
}

// ---------------------------------------------------------------------------
// LU panel, nb=32, pivot candidates = first 64 logical rows (det-invariant).
// Wave 0 factors its 64x32 subpanel IN LDS (mir): each lane owns a row;
// pivoting is metadata (done-flags / winner list), pivot row is a broadcast
// LDS read, elimination is read-fma-write on own LDS row. Zero barriers and
// zero row-shuffles in the factor loop. Winners take logical positions
// 0..31 (win order), non-winners 32..63 (lane-rank order); permutation
// parity via inversion count. Trailing rows then TRSM in parallel against
// compact-staged U11/dinv (one barrier). Linv = L11^{-1} emitted for k_gemm.
// ---------------------------------------------------------------------------
__global__ __launch_bounds__(512)
void k_panel(float2* __restrict__ Mb, float2* __restrict__ LinvG,
             int* __restrict__ rowmap, int* __restrict__ swapc, int col0){
  int k = blockIdx.x;
  float2* Mk = Mb + (size_t)k*512*512;
  int R = 512 - col0;
  int R64 = R < 64 ? R : 64;
  int rl = threadIdx.x;
  bool active = rl < R;
  int wv = rl >> 6;
  __shared__ float2 mir[64*33];
  __shared__ float2 Us[NB*33];
  __shared__ float2 dinv[NB];
  __shared__ float2 Ls[NB*NB];
  __shared__ float2 Yv[NB*NB];
  __shared__ int winslot[NB];
  __shared__ int newposS[64];
  int rm_orig = active ? rowmap[k*512 + col0 + rl] : 0;
  float2 X[NB];
  if (rl >= 64 && active){
    const float4* rp = (const float4*)(Mk + (size_t)rm_orig*512 + col0);
    #pragma unroll
    for (int q=0;q<NB/2;++q){ float4 v = rp[q]; X[2*q]=make_float2(v.x,v.y); X[2*q+1]=make_float2(v.z,v.w); }
  }
  if (wv == 0){
    if (rl < R64){
      const float4* rp = (const float4*)(Mk + (size_t)rm_orig*512 + col0);
      #pragma unroll
      for (int q=0;q<NB/2;++q){
        float4 v = rp[q];
        mir[rl*33+2*q]   = make_float2(v.x,v.y);
        mir[rl*33+2*q+1] = make_float2(v.z,v.w);
      }
    }
    bool done = false;
    int winpos = 0;
    for (int cc=0; cc<NB; ++cc){
      bool cand = (rl < R64) && !done;
      float2 cv = make_float2(0.f,0.f);
      if (cand) cv = mir[rl*33+cc];
      float val = cand ? fmaf(cv.x,cv.x,cv.y*cv.y) : -1.f;
      int idx = rl;
      #pragma unroll
      for (int off=32; off>0; off>>=1){
        float ov = __shfl_xor(val, off);
        int   oi = __shfl_xor(idx, off);
        if (ov > val || (ov == val && oi < idx)){ val = ov; idx = oi; }
      }
      int p = idx;                   // wave-uniform winner slot
      if (rl == 0) winslot[cc] = p;
      if (rl == p){ done = true; winpos = cc; }
      float2 dg = mir[p*33+cc];      // broadcast read
      float dn = 1.f/fmaf(dg.x,dg.x,dg.y*dg.y);
      float2 inv = make_float2(dg.x*dn, -dg.y*dn);
      if (cand && rl != p){
        float2 l = cmul(cv, inv);
        mir[rl*33+cc] = l;
        for (int j=cc+1; j<NB; ++j){
          float2 pr = mir[p*33+j];
          float2 xv = mir[rl*33+j];
          xv.x = fmaf(-l.x, pr.x, fmaf( l.y, pr.y, xv.x));
          xv.y = fmaf(-l.x, pr.y, fmaf(-l.y, pr.x, xv.y));
          mir[rl*33+j] = xv;
        }
      }
    }
    // logical reassignment + rowmap + writeback + parity
    unsigned long long nwmask = __ballot(rl < R64 && !done);
    int np = 0;
    if (rl < R64){
      np = done ? winpos : (NB + (int)__popcll(nwmask & ((1ull<<rl)-1ull)));
      newposS[rl] = np;
      rowmap[k*512 + col0 + np] = rm_orig;
      float4* wp = (float4*)(Mk + (size_t)rm_orig*512 + col0);
      #pragma unroll
      for (int q=0;q<NB/2;++q){
        float2 a = mir[rl*33+2*q], bq = mir[rl*33+2*q+1];
        wp[q] = make_float4(a.x,a.y,bq.x,bq.y);
      }
    }
    {
      int cnt = 0;
      for (int t=0;t<R64;++t){
        int nt = newposS[t];
        if (rl < R64 && t > rl && nt < np) cnt++;
      }
      #pragma unroll
      for (int off=32; off>0; off>>=1) cnt += __shfl_xor(cnt, off);
      if (rl == 0) swapc[k] += cnt;
    }
    // stage compact Us / dinv / Ls from winners
    if (rl < NB){
      int ws = winslot[rl];
      #pragma unroll
      for (int j=0;j<NB;++j){
        float2 v = mir[ws*33+j];
        Us[rl*33+j] = v;
        float2 lv;
        if      (j <  rl) lv = v;
        else if (j == rl) lv = make_float2(1.f,0.f);
        else              lv = make_float2(0.f,0.f);
        Ls[rl*NB+j] = lv;
      }
      float2 d = Us[rl*33+rl];
      float dn = 1.f/fmaf(d.x,d.x,d.y*d.y);
      dinv[rl] = make_float2(d.x*dn, -d.y*dn);
    }
  }
  __syncthreads();
  // trailing rows: TRSM x·U11 = a  (row-wise forward substitution)
  if (rl >= 64 && active){
    #pragma unroll
    for (int j=0;j<NB;++j){
      float2 t = X[j];
      #pragma unroll
      for (int q=0;q<NB;++q){
        if (q < j){
          float2 u = Us[q*33+j];
          t.x = fmaf(-X[q].x, u.x, fmaf( X[q].y, u.y, t.x));
          t.y = fmaf(-X[q].x, u.y, fmaf(-X[q].y, u.x, t.y));
        }
      }
      X[j] = cmul(t, dinv[j]);
    }
    float4* wp = (float4*)(Mk + (size_t)rm_orig*512 + col0);
    #pragma unroll
    for (int q=0;q<NB/2;++q) wp[q] = make_float4(X[2*q].x,X[2*q].y,X[2*q+1].x,X[2*q+1].y);
  }
  // Linv = L11^{-1} (threads 0..31, one wave, intra-wave LDS ordering)
  if (rl < NB){
    for (int i=0;i<NB;++i){
      float2 acc = (i==rl)? make_float2(1.f,0.f) : make_float2(0.f,0.f);
      for (int q=rl; q<i; ++q){
        float2 lv = Ls[i*NB+q];
        float2 yv = Yv[q*NB+rl];
        acc.x = fmaf(-lv.x, yv.x, fmaf( lv.y, yv.y, acc.x));
        acc.y = fmaf(-lv.x, yv.y, fmaf(-lv.y, yv.x, acc.y));
      }
      Yv[i*NB+rl] = acc;
    }
  }
  __syncthreads();
  {
    float4* dst = (float4*)(LinvG + (size_t)k*(NB*NB));
    const float4* src = (const float4*)Yv;
    for (int q=rl; q<NB*NB/2; q+=blockDim.x) dst[q] = src[q];
  }
}

// trailing update with fused TRSM: Bs = Linv @ A12 computed on the fly
// (U12 is never materialized). A22 -= L21 @ Bs (K=32), 32x32 tiles.
__global__ __launch_bounds__(256) void k_gemm(float2* __restrict__ Mb, const float2* __restrict__ LinvG,
                                              const int* __restrict__ rowmap, int col0){
  int k = blockIdx.z;
  float2* Mk = Mb + (size_t)k*512*512;
  int e0 = col0 + NB;
  int r0 = e0 + blockIdx.x*32;
  int j0c = e0 + blockIdx.y*32;
  int tid = threadIdx.x;
  int jl = tid & 31, rg = tid >> 5;
  __shared__ float2 As[NB*33];
  __shared__ float2 Bs[NB*33];
  __shared__ float2 Av[NB*33];
  __shared__ float2 Li[NB*NB];
  __shared__ int prA[32];
  __shared__ int prB[NB];
  if (tid < 32) prA[tid] = rowmap[k*512 + r0 + tid];
  else if (tid < 64) prB[tid-32] = rowmap[k*512 + col0 + (tid-32)];
  {
    const float4* src = (const float4*)(LinvG + (size_t)k*(NB*NB));
    float4* dst = (float4*)Li;
    for (int q=tid; q<NB*NB/2; q+=256) dst[q] = src[q];
  }
  __syncthreads();
  #pragma unroll
  for (int s=0;s<4;++s){
    int a = rg + 8*s;
    Av[a*33 + jl] = Mk[(size_t)prB[a]*512 + j0c + jl];
  }
  for (int t=tid; t<1024; t+=256){
    int rl = t >> 5, kk = t & 31;
    As[kk*33+rl] = Mk[(size_t)prA[rl]*512 + col0 + kk];
  }
  __syncthreads();
  #pragma unroll
  for (int s=0;s<4;++s){
    int m = rg + 8*s;
    float2 acc = make_float2(0.f,0.f);
    #pragma unroll 8
    for (int a=0;a<NB;++a) cfma(acc, Li[m*NB+a], Av[a*33+jl]);
    Bs[m*33+jl] = acc;
  }
  __syncthreads();
  int i0 = (tid >> 4)*2, j0 = (tid & 15)*2;
  float2 a00={0,0},a01={0,0},a10={0,0},a11={0,0};
  #pragma unroll 16
  for (int kk=0;kk<NB;++kk){
    float2 A0 = As[kk*33+i0], A1 = As[kk*33+i0+1];
    float2 B0 = Bs[kk*33+j0], B1 = Bs[kk*33+j0+1];
    cfma(a00,A0,B0); cfma(a01,A0,B1); cfma(a10,A1,B0); cfma(a11,A1,B1);
  }
  size_t ro0 = (size_t)prA[i0]*512 + j0c + j0;
  size_t ro1 = (size_t)prA[i0+1]*512 + j0c + j0;
  float2 c0 = Mk[ro0];   c0.x-=a00.x; c0.y-=a00.y; Mk[ro0]=c0;
  float2 c1 = Mk[ro0+1]; c1.x-=a01.x; c1.y-=a01.y; Mk[ro0+1]=c1;
  float2 c2 = Mk[ro1];   c2.x-=a10.x; c2.y-=a10.y; Mk[ro1]=c2;
  float2 c3 = Mk[ro1+1]; c3.x-=a11.x; c3.y-=a11.y; Mk[ro1+1]=c3;
}

// final: logabs/phase per k from U diag (via rowmap) + swap parity; log-sum-exp combine
__global__ void k_det(const float2* __restrict__ Mb, const int* __restrict__ rowmap,
                      const int* __restrict__ swapc, float* __restrict__ out, int out_size){
  int tid = threadIdx.x;
  int k = tid >> 6, lane = tid & 63;
  const float2* Mk = Mb + (size_t)k*512*512;
  double la = 0.0, ang = 0.0;
  for (int q=0;q<8;++q){
    int i = lane*8 + q;
    int pr = rowmap[k*512 + i];
    float2 u = Mk[(size_t)pr*512+i];
    double re = (double)u.x, im = (double)u.y;
    la += 0.5*log(re*re + im*im);
    ang += atan2(im, re);
  }
  #pragma unroll
  for (int off=32; off>0; off>>=1){
    la += __shfl_down(la, off);
    ang += __shfl_down(ang, off);
  }
  __shared__ double las[4], angs[4];
  if (lane==0){
    las[k] = la;
    angs[k] = ang + 3.14159265358979323846*(double)(swapc[k] & 1);
  }
  __syncthreads();
  if (tid==0){
    double mx = las[0];
    for (int q=1;q<4;++q) mx = fmax(mx, las[q]);
    double sre=0.0, sim=0.0;
    for (int q=0;q<4;++q){
      double w = exp(las[q]-mx);
      sre += w*cos(angs[q]);
      sim += w*sin(angs[q]);
    }
    double mag = sqrt(sre*sre+sim*sim);
    out[0] = (float)(log(mag)+mx);
    if (out_size > 1) out[1] = (float)atan2(sim, sre);
    for (int q=2;q<out_size;++q) out[q] = 0.f;
  }
}

extern "C" void kernel_launch(void* const* d_in, const int* in_sizes, int n_in,
                              void* d_out, int out_size, void* d_ws, size_t ws_size,
                              hipStream_t stream){
  const float* sx   = (const float*)d_in[0];
  const float* kp   = (const float*)d_in[1];
  const float* we0  = (const float*)d_in[2];
  const float* be0  = (const float*)d_in[3];
  const float* weR  = (const float*)d_in[4];
  const float* beR  = (const float*)d_in[5];
  const float* wee0 = (const float*)d_in[6];
  const float* bee0 = (const float*)d_in[7];
  const float* weeR = (const float*)d_in[8];
  const float* beeR = (const float*)d_in[9];
  const float* wep0 = (const float*)d_in[10];
  const float* bep0 = (const float*)d_in[11];
  const float* wepR = (const float*)d_in[12];
  const float* bepR = (const float*)d_in[13];
  const float* owre = (const float*)d_in[14];
  const float* owim = (const float*)d_in[15];
  const float* obre = (const float*)d_in[16];
  const float* obim = (const float*)d_in[17];
  const float* wdet = (const float*)d_in[18];
  const float* bfw  = (const float*)d_in[19];
  const float* mw1  = (const float*)d_in[20];
  const float* mb1  = (const float*)d_in[21];
  const float* mw2  = (const float*)d_in[22];
  const float* mb2  = (const float*)d_in[23];

  char* ws = (char*)d_ws;
  size_t off = 0;
  auto alloc = [&](size_t bytes)->char*{
    char* p = ws + off;
    off = (off + bytes + 255) & ~(size_t)255;
    return p;
  };
  ushort* ee   = (ushort*)alloc(33554432);
  ushort* ep   = (ushort*)alloc(33554432);
  float2* Mb   = (float2*)alloc(8388608);
  float2* U    = (float2*)alloc(2097152);
  float2* V    = (float2*)alloc(2097152);
  float2* T    = (float2*)alloc(1048576);
  float*  eS   = (float*)alloc(1048576);
  float*  ore  = (float*)alloc(262144);
  float*  oim  = (float*)alloc(262144);
  float*  z    = (float*)alloc(12288);
  float*  fdet = (float*)alloc(8192);
  float2* Linv = (float2*)alloc(131072);
  int*    rowmap = (int*)alloc(8192);
  char*   zst  = ws + off;
  float*  g2a0 = (float*)alloc(126976);
  float*  g2b0 = (float*)alloc(126976);
  float*  g30  = (float*)alloc(126976);
  float*  geeA = (float*)alloc(196608);
  float*  geeB = (float*)alloc(196608);
  float*  gep  = (float*)alloc(196608);
  float*  g1s  = (float*)alloc(1536);
  int*    swpc = (int*)alloc(16);
  int zn = (int)(((char*)(swpc+4) - zst)/4);

  float* e1 = eS;           float* e2 = eS + 65536;
  float* e3 = eS + 131072;  float* e4 = eS + 196608;
  float* geeA1 = geeA;      float* geeA2 = geeA+16384; float* geeA3 = geeA+32768;
  float* geeB1 = geeB;      float* geeB2 = geeB+16384; float* geeB3 = geeB+32768;
  float* gep1  = gep;       float* gep2  = gep+16384;  float* gep3  = gep+32768;
  float* g1s1 = g1s; float* g1s2 = g1s+128; float* g1s3 = g1s+256;

  k_zero<<<256,256,0,stream>>>((float*)zst, zn);
  k_iota<<<8,256,0,stream>>>(rowmap);
  k_pair0<<<4096,256,0,stream>>>(sx, wee0, bee0, ee, 1, g2a0, g2b0);
  k_pair0<<<4096,256,0,stream>>>(sx, wep0, bep0, ep, 0, g30, g30);
  k_e0<<<256,256,0,stream>>>(kp, g2a0, g2b0, g30, we0, be0, e1, g1s1);
  k_gee<<<128,256,0,stream>>>(ee, geeA1, geeB1);
  k_gep<<<256,256,0,stream>>>(ep, gep1);
  k_eupd<<<256,256,0,stream>>>(e1, e2, weR, beR, g1s1, geeA1, geeB1, gep1, g1s2);
  k_pairU<<<4096,256,0,stream>>>(ee, weeR, beeR);
  k_pairU<<<4096,256,0,stream>>>(ep, wepR, bepR);
  k_gee<<<128,256,0,stream>>>(ee, geeA2, geeB2);
  k_gep<<<256,256,0,stream>>>(ep, gep2);
  k_eupd<<<256,256,0,stream>>>(e2, e3, weR+240*64, beR+64, g1s2, geeA2, geeB2, gep2, g1s3);
  k_pairU<<<4096,256,0,stream>>>(ee, weeR+256, beeR+16);
  k_pairU<<<4096,256,0,stream>>>(ep, wepR+256, bepR+16);
  k_gee<<<128,256,0,stream>>>(ee, geeA3, geeB3);
  k_gep<<<256,256,0,stream>>>(ep, gep3);
  k_eupd<<<256,256,0,stream>>>(e3, e4, weR+2*240*64, beR+128, g1s3, geeA3, geeB3, gep3, nullptr);
  k_orbz<<<256,256,0,stream>>>(e4, owre, owim, obre, obim, bfw, sx, ore, oim, z);
  k_fdet<<<8,256,0,stream>>>(kp, mw1, mb1, mw2, mb2, fdet);
  k_uv<<<2048,256,0,stream>>>(kp, z, U, V);
  k_T<<<512,256,0,stream>>>(ore, oim, wdet, T);
  k_M<<<1024,256,0,stream>>>(U, V, fdet, T, ore, oim, Mb);
  for (int tpan=0;tpan<16;++tpan){
    int col0 = tpan*NB;
    int R = 512 - col0;
    int Rpad = (R + 63) & ~63;
    k_panel<<<4, Rpad, 0, stream>>>(Mb, Linv, rowmap, swpc, col0);
    if (tpan < 15){
      int nch = 15 - tpan;
      k_gemm<<<dim3(nch,nch,4),256,0,stream>>>(Mb, Linv, rowmap, col0);
    }
  }
  k_det<<<1,256,0,stream>>>(Mb, rowmap, swpc, (float*)d_out, out_size);
  (void)in_sizes; (void)n_in; (void)ws_size;
}